// Round 1
// baseline (364.015 us; speedup 1.0000x reference)
//
#include <hip/hip_runtime.h>
#include <hip/hip_bf16.h>

#define N_NODES 100000
#define D 64

// One wave (64 lanes) per edge: lane i moves feature[src][i] -> atomicAdd out[dst][i].
__global__ void gcn_scatter(const float* __restrict__ feat,
                            const int* __restrict__ src,
                            const int* __restrict__ dst,
                            float* __restrict__ out,
                            float* __restrict__ deg,
                            int n_edges) {
    long long gtid = (long long)blockIdx.x * blockDim.x + threadIdx.x;
    int edge = (int)(gtid >> 6);
    int lane = threadIdx.x & 63;
    if (edge >= n_edges) return;
    int s = src[edge];
    int d = dst[edge];
    float v = feat[(long long)s * D + lane];
    atomicAdd(&out[(long long)d * D + lane], v);
    if (lane == 0) atomicAdd(&deg[d], 1.0f);
}

// out[n,d] = deg[n] > 0 ? sum/deg : 0
__global__ void gcn_finalize(float* __restrict__ out,
                             const float* __restrict__ deg,
                             int total) {
    int i = blockIdx.x * blockDim.x + threadIdx.x;
    if (i >= total) return;
    float dg = deg[i >> 6];
    out[i] = (dg > 0.0f) ? out[i] / dg : 0.0f;
}

extern "C" void kernel_launch(void* const* d_in, const int* in_sizes, int n_in,
                              void* d_out, int out_size, void* d_ws, size_t ws_size,
                              hipStream_t stream) {
    const float* feat = (const float*)d_in[0];
    const int* src = (const int*)d_in[1];
    const int* dst = (const int*)d_in[2];
    float* out = (float*)d_out;
    float* deg = (float*)d_ws;

    int n_edges = in_sizes[1];
    int total = N_NODES * D;

    // Zero accumulators (d_out and d_ws are poisoned 0xAA by the harness).
    hipMemsetAsync(out, 0, (size_t)total * sizeof(float), stream);
    hipMemsetAsync(deg, 0, (size_t)N_NODES * sizeof(float), stream);

    // One wave per edge.
    long long threads = (long long)n_edges * 64;
    int block = 256;
    int grid = (int)((threads + block - 1) / block);
    gcn_scatter<<<grid, block, 0, stream>>>(feat, src, dst, out, deg, n_edges);

    int fgrid = (total + block - 1) / block;
    gcn_finalize<<<fgrid, block, 0, stream>>>(out, deg, total);
}